// Round 2
// baseline (273.751 us; speedup 1.0000x reference)
//
#include <hip/hip_runtime.h>

typedef unsigned int uint;

// ---------------- weight packing (runs once per launch, 1 block) ----------------
// ws layout: [o=0..63][ 0..15 : W1t row o (= W1[c][o]) | 16..31 : W2 row o ], then ws[2048+o] = b1[o]
__global__ void pack_weights(const float* __restrict__ W1, const float* __restrict__ b1,
                             const float* __restrict__ W2, float* __restrict__ ws) {
    int t = threadIdx.x;
    for (int idx = t; idx < 1024; idx += 256) {
        int o = idx >> 4, c = idx & 15;
        ws[o * 32 + c]      = W1[c * 64 + o];   // W1 is (16,64) row-major
        ws[o * 32 + 16 + c] = W2[o * 16 + c];   // W2 is (64,16) row-major
    }
    if (t < 64) ws[2048 + t] = b1[t];
}

// ---------------- bf16 pack/unpack for the pe stash ----------------
__device__ __forceinline__ uint packbf2(float a, float b) {
    uint ua = __builtin_bit_cast(uint, a);
    uint ub = __builtin_bit_cast(uint, b);
    ua = (ua + 0x7FFFu + ((ua >> 16) & 1u)) >> 16;          // RNE to bf16, low half
    ub = (ub + 0x7FFFu + ((ub >> 16) & 1u)) & 0xFFFF0000u;  // RNE to bf16, high half
    return ua | ub;
}
__device__ __forceinline__ float unpLo(uint u) { return __builtin_bit_cast(float, u << 16); }
__device__ __forceinline__ float unpHi(uint u) { return __builtin_bit_cast(float, u & 0xFFFF0000u); }

// 16-term layer-1 FMA chain (weights arrive as SGPR-resident float4s)
#define L1FMA(hv, X, A0, A1, A2, A3) do { \
    hv = fmaf((X)[0],  (A0).x, hv); hv = fmaf((X)[1],  (A0).y, hv); \
    hv = fmaf((X)[2],  (A0).z, hv); hv = fmaf((X)[3],  (A0).w, hv); \
    hv = fmaf((X)[4],  (A1).x, hv); hv = fmaf((X)[5],  (A1).y, hv); \
    hv = fmaf((X)[6],  (A1).z, hv); hv = fmaf((X)[7],  (A1).w, hv); \
    hv = fmaf((X)[8],  (A2).x, hv); hv = fmaf((X)[9],  (A2).y, hv); \
    hv = fmaf((X)[10], (A2).z, hv); hv = fmaf((X)[11], (A2).w, hv); \
    hv = fmaf((X)[12], (A3).x, hv); hv = fmaf((X)[13], (A3).y, hv); \
    hv = fmaf((X)[14], (A3).z, hv); hv = fmaf((X)[15], (A3).w, hv); \
} while (0)

#define L2FMA(S, hv, C0, C1, C2, C3) do { \
    (S)[0]  = fmaf(hv, (C0).x, (S)[0]);  (S)[1]  = fmaf(hv, (C0).y, (S)[1]);  \
    (S)[2]  = fmaf(hv, (C0).z, (S)[2]);  (S)[3]  = fmaf(hv, (C0).w, (S)[3]);  \
    (S)[4]  = fmaf(hv, (C1).x, (S)[4]);  (S)[5]  = fmaf(hv, (C1).y, (S)[5]);  \
    (S)[6]  = fmaf(hv, (C1).z, (S)[6]);  (S)[7]  = fmaf(hv, (C1).w, (S)[7]);  \
    (S)[8]  = fmaf(hv, (C2).x, (S)[8]);  (S)[9]  = fmaf(hv, (C2).y, (S)[9]);  \
    (S)[10] = fmaf(hv, (C2).z, (S)[10]); (S)[11] = fmaf(hv, (C2).w, (S)[11]); \
    (S)[12] = fmaf(hv, (C3).x, (S)[12]); (S)[13] = fmaf(hv, (C3).y, (S)[13]); \
    (S)[14] = fmaf(hv, (C3).z, (S)[14]); (S)[15] = fmaf(hv, (C3).w, (S)[15]); \
} while (0)

// ---------------- one chunk of NJ neighbors ----------------
template <int NJ>
__device__ __forceinline__ void do_chunk(
    const float* __restrict__ q, const float* __restrict__ k,
    const float* __restrict__ v, const float* __restrict__ pe,
    const float* __restrict__ ws,
    size_t qbase, size_t rowbase, int j0, int tid,
    uint2* __restrict__ stash, float lsum[16], float acc[16])
{
    float x[NJ][16];

    // q row (reloaded per chunk: L1/L2-hot, keeps it out of the persistent live set)
    float qr[16];
    {
        const float4* q4 = (const float4*)(q + qbase);
        #pragma unroll
        for (int i = 0; i < 4; ++i) {
            float4 t = q4[i];
            qr[4*i+0] = t.x; qr[4*i+1] = t.y; qr[4*i+2] = t.z; qr[4*i+3] = t.w;
        }
    }

    // phase A: build x = q - k + pe; stash pe (bf16) in LDS for phase C
    #pragma unroll
    for (int jj = 0; jj < NJ; ++jj) {
        const size_t base = rowbase + (size_t)(j0 + jj) * 64;
        const float4* k4 = (const float4*)(k + base);
        const float4* p4 = (const float4*)(pe + base);
        #pragma unroll
        for (int i = 0; i < 4; ++i) {
            float4 kk = k4[i], pp = p4[i];
            x[jj][4*i+0] = qr[4*i+0] - kk.x + pp.x;
            x[jj][4*i+1] = qr[4*i+1] - kk.y + pp.y;
            x[jj][4*i+2] = qr[4*i+2] - kk.z + pp.z;
            x[jj][4*i+3] = qr[4*i+3] - kk.w + pp.w;
            uint2 st;
            st.x = packbf2(pp.x, pp.y);
            st.y = packbf2(pp.z, pp.w);
            stash[(jj*4 + i)*256 + tid] = st;
        }
    }

    // phase B: MLP 16 -> 64(relu) -> 16, weights via uniform scalar loads from ws
    float s[NJ][16];
    #pragma unroll
    for (int jj = 0; jj < NJ; ++jj)
        #pragma unroll
        for (int c = 0; c < 16; ++c) s[jj][c] = 0.f;

    const float* wsb = ws + 2048;
    #pragma unroll 2
    for (int o = 0; o < 64; ++o) {
        const float4* w4 = (const float4*)(ws + o * 32);
        float4 a0 = w4[0], a1 = w4[1], a2 = w4[2], a3 = w4[3];  // W1t row o
        float4 c0 = w4[4], c1 = w4[5], c2 = w4[6], c3 = w4[7];  // W2  row o
        float  bb = wsb[o];
        #pragma unroll
        for (int jj = 0; jj < NJ; ++jj) {
            float hv = bb;
            L1FMA(hv, x[jj], a0, a1, a2, a3);
            hv = fmaxf(hv, 0.f);
            L2FMA(s[jj], hv, c0, c1, c2, c3);
        }
    }
    // b2 omitted: softmax over neighbors is shift-invariant in b2.

    // phase C: e = exp(s); online accumulate e and e*(v+pe)
    #pragma unroll
    for (int jj = 0; jj < NJ; ++jj) {
        const size_t base = rowbase + (size_t)(j0 + jj) * 64;
        const float4* v4 = (const float4*)(v + base);
        #pragma unroll
        for (int i = 0; i < 4; ++i) {
            float4 vv = v4[i];
            uint2 st = stash[(jj*4 + i)*256 + tid];
            float p0 = unpLo(st.x), p1 = unpHi(st.x);
            float p2 = unpLo(st.y), p3 = unpHi(st.y);
            float e0 = __expf(s[jj][4*i+0]);
            float e1 = __expf(s[jj][4*i+1]);
            float e2 = __expf(s[jj][4*i+2]);
            float e3 = __expf(s[jj][4*i+3]);
            lsum[4*i+0] += e0; lsum[4*i+1] += e1;
            lsum[4*i+2] += e2; lsum[4*i+3] += e3;
            acc[4*i+0] = fmaf(e0, vv.x + p0, acc[4*i+0]);
            acc[4*i+1] = fmaf(e1, vv.y + p1, acc[4*i+1]);
            acc[4*i+2] = fmaf(e2, vv.z + p2, acc[4*i+2]);
            acc[4*i+3] = fmaf(e3, vv.w + p3, acc[4*i+3]);
        }
    }
}

// ---------------- main kernel ----------------
// one thread per (b, p, head) row; no bounds check (grid divides work exactly);
// fully uniform control flow so weight loads scalarize to s_load.
__global__ __launch_bounds__(256, 4)
void subattn_kernel(const float* __restrict__ q, const float* __restrict__ k,
                    const float* __restrict__ v, const float* __restrict__ pe,
                    const float* __restrict__ ws, float* __restrict__ out)
{
    __shared__ uint2 stash[8 * 256];   // per-thread private bf16 pe stash (16 KB)

    const int tid = threadIdx.x;
    const int r   = blockIdx.x * 256 + tid;
    const int h   = r & 3;
    const int bp  = r >> 2;
    const size_t qbase   = (size_t)bp * 64 + h * 16;
    const size_t rowbase = (size_t)bp * 576 + h * 16;   // 9*64 = 576

    float lsum[16], acc[16];
    #pragma unroll
    for (int i = 0; i < 16; ++i) { lsum[i] = 0.f; acc[i] = 0.f; }

    do_chunk<2>(q, k, v, pe, ws, qbase, rowbase, 0, tid, stash, lsum, acc);
    do_chunk<2>(q, k, v, pe, ws, qbase, rowbase, 2, tid, stash, lsum, acc);
    do_chunk<2>(q, k, v, pe, ws, qbase, rowbase, 4, tid, stash, lsum, acc);
    do_chunk<2>(q, k, v, pe, ws, qbase, rowbase, 6, tid, stash, lsum, acc);
    do_chunk<1>(q, k, v, pe, ws, qbase, rowbase, 8, tid, stash, lsum, acc);

    float4* o4 = (float4*)(out + qbase);
    #pragma unroll
    for (int i = 0; i < 4; ++i) {
        float4 t;
        t.x = __fdividef(acc[4*i+0], lsum[4*i+0]);
        t.y = __fdividef(acc[4*i+1], lsum[4*i+1]);
        t.z = __fdividef(acc[4*i+2], lsum[4*i+2]);
        t.w = __fdividef(acc[4*i+3], lsum[4*i+3]);
        o4[i] = t;
    }
}

extern "C" void kernel_launch(void* const* d_in, const int* in_sizes, int n_in,
                              void* d_out, int out_size, void* d_ws, size_t ws_size,
                              hipStream_t stream) {
    const float* q  = (const float*)d_in[0];
    const float* k  = (const float*)d_in[1];
    const float* v  = (const float*)d_in[2];
    const float* pe = (const float*)d_in[3];
    const float* W1 = (const float*)d_in[4];
    const float* b1 = (const float*)d_in[5];
    const float* W2 = (const float*)d_in[6];
    // d_in[7] = b2: cancels in softmax over neighbors.
    float* out = (float*)d_out;
    float* ws  = (float*)d_ws;   // needs (2048+64)*4 = 8448 B

    pack_weights<<<1, 256, 0, stream>>>(W1, b1, W2, ws);

    const int nrows = in_sizes[0] / 16;     // (bs*num_p) * 4 heads = 262144
    const int grid  = nrows / 256;          // divides exactly (1024 blocks)
    subattn_kernel<<<grid, 256, 0, stream>>>(q, k, v, pe, ws, out);
}

// Round 3
// 148.942 us; speedup vs baseline: 1.8380x; 1.8380x over previous
//
#include <hip/hip_runtime.h>

// ---------------- weight packing (1 tiny block, runs each launch) ----------------
// ws[o*32 + 0..15]  = W1[c][o]   (W1 is (16,64) row-major -> transposed row o)
// ws[o*32 + 16..31] = W2[o][c]   (W2 is (64,16) row-major -> row o)
// ws[2048 + o]      = b1[o]
__global__ void pack_weights(const float* __restrict__ W1, const float* __restrict__ b1,
                             const float* __restrict__ W2, float* __restrict__ ws) {
    int t = threadIdx.x;
    for (int idx = t; idx < 1024; idx += 256) {
        int o = idx >> 4, c = idx & 15;
        ws[o * 32 + c]      = W1[c * 64 + o];
        ws[o * 32 + 16 + c] = W2[o * 16 + c];
    }
    if (t < 64) ws[2048 + t] = b1[t];
}

// ---------------- main kernel ----------------
// One thread per (b, p, head) row. One neighbor in flight at a time -> live set
// ~112 VGPRs. waves_per_eu pinned to (4,4): VGPR budget exactly 128, allocator
// cannot chase 8-wave occupancy with 64 regs (round-2 failure mode: 392 MB of
// scratch traffic). Weights are wave-uniform -> scalar (s_load) operands.
__global__ __launch_bounds__(256) __attribute__((amdgpu_waves_per_eu(4, 4)))
void subattn_kernel(const float* __restrict__ q, const float* __restrict__ k,
                    const float* __restrict__ v, const float* __restrict__ pe,
                    const float* __restrict__ ws, float* __restrict__ out)
{
    const int tid = threadIdx.x;
    const int r   = blockIdx.x * 256 + tid;
    const int h   = r & 3;
    const int bp  = r >> 2;
    const size_t qbase   = (size_t)bp * 64 + h * 16;
    const size_t rowbase = (size_t)bp * 576 + h * 16;   // 9 neighbors * 64 ch

    // q row, held in registers for all 9 neighbors
    float qr[16];
    {
        const float4* q4 = (const float4*)(q + qbase);
        #pragma unroll
        for (int i = 0; i < 4; ++i) {
            float4 t = q4[i];
            qr[4*i+0] = t.x; qr[4*i+1] = t.y; qr[4*i+2] = t.z; qr[4*i+3] = t.w;
        }
    }

    float lsum[16], acc[16];
    #pragma unroll
    for (int i = 0; i < 16; ++i) { lsum[i] = 0.f; acc[i] = 0.f; }

    const float* wsb = ws + 2048;

    for (int j = 0; j < 9; ++j) {          // NOT unrolled: keeps I-cache + regs small
        const size_t base = rowbase + (size_t)j * 64;
        const float4* k4 = (const float4*)(k  + base);
        const float4* p4 = (const float4*)(pe + base);
        const float4* v4 = (const float4*)(v  + base);

        float x[16], vp[16];
        #pragma unroll
        for (int i = 0; i < 4; ++i) {
            float4 kk = k4[i], pp = p4[i], vv = v4[i];
            x [4*i+0] = qr[4*i+0] - kk.x + pp.x;
            x [4*i+1] = qr[4*i+1] - kk.y + pp.y;
            x [4*i+2] = qr[4*i+2] - kk.z + pp.z;
            x [4*i+3] = qr[4*i+3] - kk.w + pp.w;
            vp[4*i+0] = vv.x + pp.x;
            vp[4*i+1] = vv.y + pp.y;
            vp[4*i+2] = vv.z + pp.z;
            vp[4*i+3] = vv.w + pp.w;
        }

        float s[16];
        #pragma unroll
        for (int c = 0; c < 16; ++c) s[c] = 0.f;

        // MLP 16 -> 64(relu) -> 16; weights come in as scalar (uniform) loads
        #pragma unroll 2
        for (int o = 0; o < 64; ++o) {
            const float4* w4 = (const float4*)(ws + o * 32);
            float4 a0 = w4[0], a1 = w4[1], a2 = w4[2], a3 = w4[3];  // W1t row o
            float4 c0 = w4[4], c1 = w4[5], c2 = w4[6], c3 = w4[7];  // W2  row o
            float hv = wsb[o];
            hv = fmaf(x[0],  a0.x, hv); hv = fmaf(x[1],  a0.y, hv);
            hv = fmaf(x[2],  a0.z, hv); hv = fmaf(x[3],  a0.w, hv);
            hv = fmaf(x[4],  a1.x, hv); hv = fmaf(x[5],  a1.y, hv);
            hv = fmaf(x[6],  a1.z, hv); hv = fmaf(x[7],  a1.w, hv);
            hv = fmaf(x[8],  a2.x, hv); hv = fmaf(x[9],  a2.y, hv);
            hv = fmaf(x[10], a2.z, hv); hv = fmaf(x[11], a2.w, hv);
            hv = fmaf(x[12], a3.x, hv); hv = fmaf(x[13], a3.y, hv);
            hv = fmaf(x[14], a3.z, hv); hv = fmaf(x[15], a3.w, hv);
            hv = fmaxf(hv, 0.f);
            s[0]  = fmaf(hv, c0.x, s[0]);  s[1]  = fmaf(hv, c0.y, s[1]);
            s[2]  = fmaf(hv, c0.z, s[2]);  s[3]  = fmaf(hv, c0.w, s[3]);
            s[4]  = fmaf(hv, c1.x, s[4]);  s[5]  = fmaf(hv, c1.y, s[5]);
            s[6]  = fmaf(hv, c1.z, s[6]);  s[7]  = fmaf(hv, c1.w, s[7]);
            s[8]  = fmaf(hv, c2.x, s[8]);  s[9]  = fmaf(hv, c2.y, s[9]);
            s[10] = fmaf(hv, c2.z, s[10]); s[11] = fmaf(hv, c2.w, s[11]);
            s[12] = fmaf(hv, c3.x, s[12]); s[13] = fmaf(hv, c3.y, s[13]);
            s[14] = fmaf(hv, c3.z, s[14]); s[15] = fmaf(hv, c3.w, s[15]);
        }
        // b2 omitted: softmax over neighbors is shift-invariant in b2.

        // online softmax accumulate (|s| small enough that no max-subtract needed)
        #pragma unroll
        for (int c = 0; c < 16; ++c) {
            float e = __expf(s[c]);
            lsum[c] += e;
            acc[c]  = fmaf(e, vp[c], acc[c]);
        }
    }

    float4* o4 = (float4*)(out + qbase);
    #pragma unroll
    for (int i = 0; i < 4; ++i) {
        float4 t;
        t.x = __fdividef(acc[4*i+0], lsum[4*i+0]);
        t.y = __fdividef(acc[4*i+1], lsum[4*i+1]);
        t.z = __fdividef(acc[4*i+2], lsum[4*i+2]);
        t.w = __fdividef(acc[4*i+3], lsum[4*i+3]);
        o4[i] = t;
    }
}

extern "C" void kernel_launch(void* const* d_in, const int* in_sizes, int n_in,
                              void* d_out, int out_size, void* d_ws, size_t ws_size,
                              hipStream_t stream) {
    const float* q  = (const float*)d_in[0];
    const float* k  = (const float*)d_in[1];
    const float* v  = (const float*)d_in[2];
    const float* pe = (const float*)d_in[3];
    const float* W1 = (const float*)d_in[4];
    const float* b1 = (const float*)d_in[5];
    const float* W2 = (const float*)d_in[6];
    // d_in[7] = b2: cancels in softmax over neighbors.
    float* out = (float*)d_out;
    float* ws  = (float*)d_ws;   // needs (2048+64)*4 = 8448 B

    pack_weights<<<1, 256, 0, stream>>>(W1, b1, W2, ws);

    const int nrows = in_sizes[0] / 16;   // (bs*num_p)*4 heads = 262144
    const int grid  = nrows / 256;        // divides exactly
    subattn_kernel<<<grid, 256, 0, stream>>>(q, k, v, pe, ws, out);
}